// Round 2
// baseline (176.250 us; speedup 1.0000x reference)
//
#include <hip/hip_runtime.h>

typedef unsigned short u16;
typedef unsigned int   u32;
typedef __attribute__((ext_vector_type(8))) short bf16x8;   // 8 bf16 in 4 VGPRs
typedef __attribute__((ext_vector_type(4))) float f32x4;

#define NN   256
#define DD   768
#define PP   65280
#define KCAT 5376   // 6*768 (mean) + 768 (root)

__device__ inline u16 f2bf(float f) {
    union { float f; u32 u; } v; v.f = f;
    u32 r = v.u + 0x7FFFu + ((v.u >> 16) & 1u);   // RNE
    return (u16)(r >> 16);
}
__device__ inline float bf2f(u16 u) {
    union { u32 u; float f; } v; v.u = ((u32)u) << 16;
    return v.f;
}
__device__ inline f32x4 mfma16(bf16x8 a, bf16x8 b, f32x4 c) {
    return __builtin_amdgcn_mfma_f32_16x16x32_bf16(a, b, c, 0, 0, 0);
}
__device__ inline u16 ld_bf(const float* p) { return f2bf(*p); }
__device__ inline u16 ld_bf(const u16* p)   { return *p; }

// ---------------- zero S/cnt + convert embed (f32) into Acat1 tail (bf16) -----
__global__ __launch_bounds__(256) void kz(u32* S, int* cnt, const float* __restrict__ embed,
                                          u16* __restrict__ Acat1) {
    int t = blockIdx.x * 256 + threadIdx.x;
    if (t < 196608) {                 // S: 1536*256 bf16 = 196608 u32 words
        S[t] = 0;
    } else if (t < 198144) {          // cnt: 1536 ints
        cnt[t - 196608] = 0;
    } else {                          // embed f32 -> bf16 into Acat1[:,4608:5376]
        int c = t - 198144;           // 0..196607
        int row = c / 768, col = c - row * 768;
        Acat1[row * KCAT + 4608 + col] = f2bf(embed[c]);
    }
}

// ---------------- scatter: S[(dst*6+rel)][src]=1, cnt++ ----------------
__global__ __launch_bounds__(256) void kscatter(const int* __restrict__ labels,
                                                u16* __restrict__ S, int* __restrict__ cnt) {
    int p = blockIdx.x * 256 + threadIdx.x;
    if (p >= PP) return;
    int lab = labels[p];
    if (lab == 6) return;             // NONE relation: dropped
    int i = p / 255, rem = p - i * 255;
    int k = rem + (rem >= i ? 1 : 0);
    int g = k * 6 + lab;
    S[g * 256 + i] = 0x3F80;          // bf16 1.0
    atomicAdd(&cnt[g], 1);
}

// ---------------- pack a row-major matrix into MFMA B-fragment layout (bf16) ---
// dst[(kt0+ktile)*ntot + (nt0+ntile)][lane][8], B[k][n], k=kt*32+(lane>>4)*8+j, n=nt*16+(lane&15)
template <typename T>
__global__ __launch_bounds__(64) void kpack(const T* __restrict__ src, int ld, int rows, int cols,
                                            u16* __restrict__ dst, int ntot, int kt0, int nt0, int ntiles) {
    int ktile = blockIdx.x / ntiles, ntile = blockIdx.x % ntiles;
    int lane = threadIdx.x;
    int m = lane & 15, hi = lane >> 4;
    int n = ntile * 16 + m;
    u16* d = dst + (((size_t)(kt0 + ktile) * ntot + (nt0 + ntile)) * 64 + lane) * 8;
#pragma unroll
    for (int j = 0; j < 8; ++j) {
        int kk = ktile * 32 + hi * 8 + j;
        d[j] = (kk < rows && n < cols) ? ld_bf(&src[(size_t)kk * ld + n]) : (u16)0;
    }
}

// ---------------- one-wave 16x16 GEMM tile, A row-major bf16, B pre-packed -----
__device__ inline f32x4 gemm_tile(const u16* __restrict__ A, int lda,
                                  const u16* __restrict__ Bp,
                                  int row0, int nt, int ntot, int ktiles) {
    int lane = threadIdx.x & 63;
    int m = lane & 15, hi = lane >> 4;
    const u16* arow = A + (size_t)(row0 + m) * lda + hi * 8;
    const u16* bptr = Bp + ((size_t)nt * 64 + lane) * 8;
    f32x4 acc = {0.f, 0.f, 0.f, 0.f};
#pragma unroll 4
    for (int kt = 0; kt < ktiles; ++kt) {
        bf16x8 a = *(const bf16x8*)(arow + kt * 32);
        bf16x8 b = *(const bf16x8*)(bptr + (size_t)kt * ntot * 512);
        acc = mfma16(a, b, acc);
    }
    return acc;
}

// ---------------- mean = (S @ X) / cnt  -> Acat[node][rel*768 + col] (bf16) ----
__global__ __launch_bounds__(256) void kmean(const u16* __restrict__ S, const u16* __restrict__ Bp,
                                             const int* __restrict__ cnt, u16* __restrict__ Acat) {
    int w = threadIdx.x >> 6;
    int tile = blockIdx.x * 4 + w;        // 4608 tiles: 96 row-tiles x 48 col-tiles
    int rt = tile / 48, nt = tile % 48;
    f32x4 acc = gemm_tile(S, 256, Bp, rt * 16, nt, 48, 8);
    int lane = threadIdx.x & 63;
    int col = nt * 16 + (lane & 15), hi = lane >> 4;
#pragma unroll
    for (int r = 0; r < 4; ++r) {
        int g = rt * 16 + hi * 4 + r;     // g = node*6 + rel
        int c = cnt[g];
        float scale = 1.0f / (float)(c > 1 ? c : 1);
        int node = g / 6, rel = g - node * 6;
        Acat[(size_t)node * KCAT + rel * DD + col] = f2bf(acc[r] * scale);
    }
}

// ---------------- conv combine: Acat[256,5376] @ Wcat -> dst (+bias, opt relu) --
template <int RELU>
__global__ __launch_bounds__(256) void kconv(const u16* __restrict__ Acat, const u16* __restrict__ Bp,
                                             const float* __restrict__ bias,
                                             u16* __restrict__ dst, int dst_ld, int dst_off) {
    int w = threadIdx.x >> 6;
    int tile = blockIdx.x * 4 + w;        // 768 tiles: 16 x 48
    int rt = tile / 48, nt = tile % 48;
    f32x4 acc = gemm_tile(Acat, KCAT, Bp, rt * 16, nt, 48, 168);
    int lane = threadIdx.x & 63;
    int col = nt * 16 + (lane & 15), hi = lane >> 4;
    float bb = bias[col];
#pragma unroll
    for (int r = 0; r < 4; ++r) {
        int g = rt * 16 + hi * 4 + r;
        float v = acc[r] + bb;
        if (RELU) v = fmaxf(v, 0.f);
        dst[(size_t)g * dst_ld + dst_off + col] = f2bf(v);
    }
}

// ---------------- A1/B1 tables: out2 @ [w1_top | w1_bot] (+b1 on A1) -> f32 ----
__global__ __launch_bounds__(256) void kab(const u16* __restrict__ out2, const u16* __restrict__ Bp,
                                           const float* __restrict__ b1, float* __restrict__ AB) {
    int w = threadIdx.x >> 6;
    int tile = blockIdx.x * 4 + w;        // 320 tiles: 16 x 20
    int rt = tile / 20, nt = tile % 20;
    f32x4 acc = gemm_tile(out2, DD, Bp, rt * 16, nt, 20, 24);
    int lane = threadIdx.x & 63;
    int j = nt * 16 + (lane & 15), hi = lane >> 4;
#pragma unroll
    for (int r = 0; r < 4; ++r) {
        int g = rt * 16 + hi * 4 + r;
        float v;
        if (j < 160) { v = (j < 150) ? acc[r] + b1[j] : 0.f; }
        else         { int jj = j - 160; v = (jj < 150) ? acc[r] : 0.f; }
        AB[(size_t)g * 320 + j] = v;
    }
}

// ---------------- fused pair MLP: h1=relu(A1[i]+B1[k]); h2=relu(h1@w2+b2); out=h2@w3+b3
__global__ __launch_bounds__(256) void kpair(const float* __restrict__ AB,
                                             const u16* __restrict__ w2p, const u16* __restrict__ w3p,
                                             const float* __restrict__ b2, const float* __restrict__ b3,
                                             float* __restrict__ out) {
    __shared__ u16 h2t[4][16][168];       // stride 168 bf16 = 336B: conflict-light transpose
    int w = threadIdx.x >> 6, lane = threadIdx.x & 63;
    int m = lane & 15, hi = lane >> 4;
    int pb = blockIdx.x * 64 + w * 16;    // 16 pairs per wave
    int p = pb + m;
    int i = p / 255, rem = p - i * 255;
    int k = rem + (rem >= i ? 1 : 0);
    const float* Ar = AB + (size_t)i * 320;        // A1 row (has +b1 folded)
    const float* Br = AB + (size_t)k * 320 + 160;  // B1 row

    // layer 1: build A-fragments of h1 directly in registers (K padded 150->160)
    bf16x8 af[5];
#pragma unroll
    for (int kk = 0; kk < 5; ++kk) {
        int c = kk * 32 + hi * 8;
        f32x4 a0 = *(const f32x4*)(Ar + c);
        f32x4 a1 = *(const f32x4*)(Ar + c + 4);
        f32x4 b0 = *(const f32x4*)(Br + c);
        f32x4 b1v = *(const f32x4*)(Br + c + 4);
        f32x4 s0 = a0 + b0, s1 = a1 + b1v;
        bf16x8 f;
#pragma unroll
        for (int e = 0; e < 4; ++e) {
            f[e]     = (short)f2bf(fmaxf(s0[e], 0.f));
            f[e + 4] = (short)f2bf(fmaxf(s1[e], 0.f));
        }
        af[kk] = f;
    }

    // layer 2: h2 = relu(h1 @ w2 + b2), write transposed into LDS
#pragma unroll
    for (int nt = 0; nt < 10; ++nt) {
        f32x4 acc = {0.f, 0.f, 0.f, 0.f};
#pragma unroll
        for (int kk = 0; kk < 5; ++kk) {
            bf16x8 b = *(const bf16x8*)(w2p + ((size_t)(kk * 10 + nt) * 64 + lane) * 8);
            acc = mfma16(af[kk], b, acc);
        }
        int col = nt * 16 + m;
        float bb = (col < 150) ? b2[col] : 0.f;
#pragma unroll
        for (int r = 0; r < 4; ++r) {
            float v = fmaxf(acc[r] + bb, 0.f);
            h2t[w][hi * 4 + r][col] = f2bf(v);
        }
    }
    __syncthreads();

    // layer 3: out = h2 @ w3 + b3
    f32x4 acc3 = {0.f, 0.f, 0.f, 0.f};
#pragma unroll
    for (int kk = 0; kk < 5; ++kk) {
        bf16x8 a = *(const bf16x8*)(&h2t[w][m][kk * 32 + hi * 8]);
        bf16x8 b = *(const bf16x8*)(w3p + ((size_t)kk * 64 + lane) * 8);
        acc3 = mfma16(a, b, acc3);
    }
    if (m < 7) {
        float bb = b3[m];
#pragma unroll
        for (int r = 0; r < 4; ++r) {
            int p2 = pb + hi * 4 + r;
            out[p2 * 7 + m] = acc3[r] + bb;
        }
    }
}

extern "C" void kernel_launch(void* const* d_in, const int* in_sizes, int n_in,
                              void* d_out, int out_size, void* d_ws, size_t ws_size,
                              hipStream_t stream) {
    const float* embed  = (const float*)d_in[0];
    const int*   labels = (const int*)d_in[1];
    const float* c1w    = (const float*)d_in[2];
    const float* c1root = (const float*)d_in[3];
    const float* c1b    = (const float*)d_in[4];
    const float* c2w    = (const float*)d_in[5];
    const float* c2root = (const float*)d_in[6];
    const float* c2b    = (const float*)d_in[7];
    // base_* (d_in[8..13]) are dead: their output is never used by the reference
    const float* cw1    = (const float*)d_in[14];
    const float* cb1    = (const float*)d_in[15];
    const float* cw2    = (const float*)d_in[16];
    const float* cb2    = (const float*)d_in[17];
    const float* cw3    = (const float*)d_in[18];
    const float* cb3    = (const float*)d_in[19];
    float* outp = (float*)d_out;
    char* ws = (char*)d_ws;

    u16*   S     = (u16*)(ws + 0);          // [1536][256] bf16        786432
    int*   cnt   = (int*)(ws + 786432);     // [1536] int              6144
    u16*   Acat1 = (u16*)(ws + 792576);     // [256][5376] bf16        2752512
    u16*   Acat2 = (u16*)(ws + 3545088);    // [256][5376] bf16        2752512
    u16*   Pemb  = (u16*)(ws + 6297600);    // packed embed            393216
    u16*   Px    = (u16*)(ws + 6690816);    // packed x                393216
    u16*   PW1   = (u16*)(ws + 7084032);    // packed Wcat1 [168][48]  8257536
    u16*   PW2   = (u16*)(ws + 15341568);   // packed Wcat2            8257536
    u16*   PC1   = (u16*)(ws + 23599104);   // packed cls_w1 [24][20]  491520
    u16*   Pw2c  = (u16*)(ws + 24090624);   // packed cls_w2 [5][10]   102400
    u16*   Pw3   = (u16*)(ws + 24193024);   // packed cls_w3 [5][1]    10240
    u16*   out2  = (u16*)(ws + 24203264);   // conv2 output bf16       393216
    float* AB    = (float*)(ws + 24596480); // [256][320] f32 A1|B1    327680

    kz<<<1542, 256, 0, stream>>>((u32*)S, cnt, embed, Acat1);
    kscatter<<<255, 256, 0, stream>>>(labels, S, cnt);

    kpack<float><<<8 * 48, 64, 0, stream>>>(embed, 768, 256, 768, Pemb, 48, 0, 0, 48);
    kpack<float><<<144 * 48, 64, 0, stream>>>(c1w, 768, 4608, 768, PW1, 48, 0, 0, 48);
    kpack<float><<<24 * 48, 64, 0, stream>>>(c1root, 768, 768, 768, PW1, 48, 144, 0, 48);
    kpack<float><<<144 * 48, 64, 0, stream>>>(c2w, 768, 4608, 768, PW2, 48, 0, 0, 48);
    kpack<float><<<24 * 48, 64, 0, stream>>>(c2root, 768, 768, 768, PW2, 48, 144, 0, 48);
    kpack<float><<<24 * 10, 64, 0, stream>>>(cw1, 150, 768, 150, PC1, 20, 0, 0, 10);
    kpack<float><<<24 * 10, 64, 0, stream>>>(cw1 + 768 * 150, 150, 768, 150, PC1, 20, 0, 10, 10);
    kpack<float><<<5 * 10, 64, 0, stream>>>(cw2, 150, 150, 150, Pw2c, 10, 0, 0, 10);
    kpack<float><<<5, 64, 0, stream>>>(cw3, 7, 150, 7, Pw3, 1, 0, 0, 1);

    kmean<<<1152, 256, 0, stream>>>(S, Pemb, cnt, Acat1);             // conv1 aggregate
    kconv<1><<<192, 256, 0, stream>>>(Acat1, PW1, c1b, Acat2, KCAT, 4608);  // x = relu(...), into Acat2 tail
    kpack<u16><<<8 * 48, 64, 0, stream>>>(Acat2 + 4608, KCAT, 256, 768, Px, 48, 0, 0, 48);
    kmean<<<1152, 256, 0, stream>>>(S, Px, cnt, Acat2);               // conv2 aggregate
    kconv<0><<<192, 256, 0, stream>>>(Acat2, PW2, c2b, out2, DD, 0);  // out2
    kab<<<80, 256, 0, stream>>>(out2, PC1, cb1, AB);                  // A1(+b1) | B1 tables
    kpair<<<1020, 256, 0, stream>>>(AB, Pw2c, Pw3, cb2, cb3, outp);   // fused pair MLP
}

// Round 3
// 127.346 us; speedup vs baseline: 1.3840x; 1.3840x over previous
//
#include <hip/hip_runtime.h>

typedef unsigned short u16;
typedef unsigned int   u32;
typedef __attribute__((ext_vector_type(8))) short bf16x8;   // 8 bf16 in 4 VGPRs
typedef __attribute__((ext_vector_type(4))) float f32x4;

#define NN   256
#define DD   768
#define PP   65280
#define KCAT 5376   // 6*768 (mean) + 768 (root)

__device__ inline u16 f2bf(float f) {
    union { float f; u32 u; } v; v.f = f;
    u32 r = v.u + 0x7FFFu + ((v.u >> 16) & 1u);   // RNE
    return (u16)(r >> 16);
}
__device__ inline f32x4 mfma16(bf16x8 a, bf16x8 b, f32x4 c) {
    return __builtin_amdgcn_mfma_f32_16x16x32_bf16(a, b, c, 0, 0, 0);
}

// pack one 32x16 tile of a row-major f32 matrix into MFMA B-fragment layout (bf16)
// dst[(kt0+ktile)*ntot + (nt0+ntile)][lane][8]; B[k][n], k=kt*32+(lane>>4)*8+j, n=nt*16+(lane&15)
__device__ inline void pack_f32(const float* __restrict__ src, int ld, int rows, int cols,
                                u16* __restrict__ dst, int ntot, int kt0, int nt0,
                                int ntiles, int tile) {
    int ktile = tile / ntiles, ntile = tile % ntiles;
    int lane = threadIdx.x & 63;
    int m = lane & 15, hi = lane >> 4;
    int n = ntile * 16 + m;
    u16 tmp[8];
#pragma unroll
    for (int j = 0; j < 8; ++j) {
        int kk = ktile * 32 + hi * 8 + j;
        tmp[j] = (kk < rows && n < cols) ? f2bf(src[(size_t)kk * ld + n]) : (u16)0;
    }
    u16* d = dst + (((size_t)(kt0 + ktile) * ntot + (nt0 + ntile)) * 64 + lane) * 8;
    *(bf16x8*)d = *(const bf16x8*)tmp;
}

// ---------------- mega setup: S+recip builder, embed tail convert, all weight packs
__global__ __launch_bounds__(256) void ksetup(
    const float* __restrict__ embed, const int* __restrict__ labels,
    const float* __restrict__ c1w, const float* __restrict__ c1root,
    const float* __restrict__ c2w, const float* __restrict__ c2root,
    const float* __restrict__ cw1, const float* __restrict__ cw2, const float* __restrict__ cw3,
    u16* __restrict__ S, float* __restrict__ recip, u16* __restrict__ Acat1,
    u16* __restrict__ Pemb, u16* __restrict__ PW1, u16* __restrict__ PW2,
    u16* __restrict__ PC1, u16* __restrict__ Pw2c, u16* __restrict__ Pw3) {
    int w = threadIdx.x >> 6, lane = threadIdx.x & 63;
    int vbid = blockIdx.x * 4 + w;
    if (vbid < 256) {
        // one wave per dst node k: build S rows (k*6+r) fully + recip, no atomics, no pre-zero
        int k = vbid;
        int lab[4];
#pragma unroll
        for (int g = 0; g < 4; ++g) {
            int i = lane + g * 64;
            lab[g] = (i == k) ? -1 : labels[i * 255 + k - (k > i ? 1 : 0)];
        }
#pragma unroll
        for (int r = 0; r < 6; ++r) {
            int c = 0;
#pragma unroll
            for (int g = 0; g < 4; ++g)
                c += __popcll(__ballot(lab[g] == r));
#pragma unroll
            for (int g = 0; g < 4; ++g) {
                int i = lane + g * 64;
                S[(k * 6 + r) * 256 + i] = (lab[g] == r) ? (u16)0x3F80 : (u16)0;
            }
            if (lane == 0) recip[k * 6 + r] = 1.0f / (float)(c > 1 ? c : 1);
        }
    } else if (vbid < 640) {
        // embed f32 -> bf16 into Acat1[:,4608:5376]
        int idx = (vbid - 256) * 512 + lane * 8;
        int row = idx / 768, col = idx - row * 768;
        f32x4 a = *(const f32x4*)(embed + idx);
        f32x4 b = *(const f32x4*)(embed + idx + 4);
        u16 tmp[8];
#pragma unroll
        for (int e = 0; e < 4; ++e) { tmp[e] = f2bf(a[e]); tmp[e + 4] = f2bf(b[e]); }
        *(bf16x8*)(Acat1 + (size_t)row * KCAT + 4608 + col) = *(const bf16x8*)tmp;
    }
    else if (vbid < 1024)  pack_f32(embed, 768, 256, 768, Pemb, 48, 0, 0, 48, vbid - 640);
    else if (vbid < 7936)  pack_f32(c1w, 768, 4608, 768, PW1, 48, 0, 0, 48, vbid - 1024);
    else if (vbid < 9088)  pack_f32(c1root, 768, 768, 768, PW1, 48, 144, 0, 48, vbid - 7936);
    else if (vbid < 16000) pack_f32(c2w, 768, 4608, 768, PW2, 48, 0, 0, 48, vbid - 9088);
    else if (vbid < 17152) pack_f32(c2root, 768, 768, 768, PW2, 48, 144, 0, 48, vbid - 16000);
    else if (vbid < 17392) pack_f32(cw1, 150, 768, 150, PC1, 20, 0, 0, 10, vbid - 17152);
    else if (vbid < 17632) pack_f32(cw1 + 768 * 150, 150, 768, 150, PC1, 20, 0, 10, 10, vbid - 17392);
    else if (vbid < 17682) pack_f32(cw2, 150, 150, 150, Pw2c, 10, 0, 0, 10, vbid - 17632);
    else if (vbid < 17687) pack_f32(cw3, 7, 150, 7, Pw3, 1, 0, 0, 1, vbid - 17682);
}

// ---------------- one-wave 16x16 GEMM tile, A row-major bf16, B pre-packed -----
__device__ inline f32x4 gemm_tile(const u16* __restrict__ A, int lda,
                                  const u16* __restrict__ Bp,
                                  int row0, int nt, int ntot, int ktiles) {
    int lane = threadIdx.x & 63;
    int m = lane & 15, hi = lane >> 4;
    const u16* arow = A + (size_t)(row0 + m) * lda + hi * 8;
    const u16* bptr = Bp + ((size_t)nt * 64 + lane) * 8;
    f32x4 acc = {0.f, 0.f, 0.f, 0.f};
#pragma unroll 4
    for (int kt = 0; kt < ktiles; ++kt) {
        bf16x8 a = *(const bf16x8*)(arow + kt * 32);
        bf16x8 b = *(const bf16x8*)(bptr + (size_t)kt * ntot * 512);
        acc = mfma16(a, b, acc);
    }
    return acc;
}

// ---------------- mean = (S @ X) * recip -> Acat[node][rel*768 + col] (bf16) ----
__global__ __launch_bounds__(256) void kmean(const u16* __restrict__ S, const u16* __restrict__ Bp,
                                             const float* __restrict__ recip, u16* __restrict__ Acat) {
    int w = threadIdx.x >> 6;
    int tile = blockIdx.x * 4 + w;        // 4608 tiles: 96 row-tiles x 48 col-tiles
    int rt = tile / 48, nt = tile % 48;
    f32x4 acc = gemm_tile(S, 256, Bp, rt * 16, nt, 48, 8);
    int lane = threadIdx.x & 63;
    int col = nt * 16 + (lane & 15), hi = lane >> 4;
#pragma unroll
    for (int r = 0; r < 4; ++r) {
        int g = rt * 16 + hi * 4 + r;     // g = node*6 + rel
        float scale = recip[g];
        int node = g / 6, rel = g - node * 6;
        Acat[(size_t)node * KCAT + rel * DD + col] = f2bf(acc[r] * scale);
    }
}

// ---------------- conv combine: Acat[256,5376] @ Wcat -> dst (+bias, opt relu) --
// Ppack != nullptr: also write result in MFMA B-fragment layout (fuses next pack)
template <int RELU>
__global__ __launch_bounds__(256) void kconv(const u16* __restrict__ Acat, const u16* __restrict__ Bp,
                                             const float* __restrict__ bias,
                                             u16* __restrict__ dst, int dst_ld, int dst_off,
                                             u16* __restrict__ Ppack) {
    int w = threadIdx.x >> 6;
    int tile = blockIdx.x * 4 + w;        // 768 tiles: 16 x 48
    int rt = tile / 48, nt = tile % 48;
    f32x4 acc = gemm_tile(Acat, KCAT, Bp, rt * 16, nt, 48, 168);
    int lane = threadIdx.x & 63;
    int m = lane & 15, hi = lane >> 4;
    int col = nt * 16 + m;
    float bb = bias[col];
#pragma unroll
    for (int r = 0; r < 4; ++r) {
        int g = rt * 16 + hi * 4 + r;
        float v = acc[r] + bb;
        if (RELU) v = fmaxf(v, 0.f);
        u16 bv = f2bf(v);
        dst[(size_t)g * dst_ld + dst_off + col] = bv;
        if (Ppack) {
            int kt = g >> 5, rem = g & 31, hi2 = rem >> 3, j = rem & 7;
            Ppack[(((size_t)kt * 48 + nt) * 64 + (hi2 * 16 + m)) * 8 + j] = bv;
        }
    }
}

// ---------------- A1/B1 tables: out2 @ [w1_top | w1_bot] (+b1 on A1) -> f32 ----
__global__ __launch_bounds__(256) void kab(const u16* __restrict__ out2, const u16* __restrict__ Bp,
                                           const float* __restrict__ b1, float* __restrict__ AB) {
    int w = threadIdx.x >> 6;
    int tile = blockIdx.x * 4 + w;        // 320 tiles: 16 x 20
    int rt = tile / 20, nt = tile % 20;
    f32x4 acc = gemm_tile(out2, DD, Bp, rt * 16, nt, 20, 24);
    int lane = threadIdx.x & 63;
    int j = nt * 16 + (lane & 15), hi = lane >> 4;
#pragma unroll
    for (int r = 0; r < 4; ++r) {
        int g = rt * 16 + hi * 4 + r;
        float v;
        if (j < 160) { v = (j < 150) ? acc[r] + b1[j] : 0.f; }
        else         { int jj = j - 160; v = (jj < 150) ? acc[r] : 0.f; }
        AB[(size_t)g * 320 + j] = v;
    }
}

// ---------------- fused pair MLP: h1=relu(A1[i]+B1[k]); h2=relu(h1@w2+b2); out=h2@w3+b3
__global__ __launch_bounds__(256) void kpair(const float* __restrict__ AB,
                                             const u16* __restrict__ w2p, const u16* __restrict__ w3p,
                                             const float* __restrict__ b2, const float* __restrict__ b3,
                                             float* __restrict__ out) {
    __shared__ u16 h2t[4][16][168];       // stride 168 bf16 = 336B: conflict-light transpose
    int w = threadIdx.x >> 6, lane = threadIdx.x & 63;
    int m = lane & 15, hi = lane >> 4;
    int pb = blockIdx.x * 64 + w * 16;    // 16 pairs per wave
    int p = pb + m;
    int i = p / 255, rem = p - i * 255;
    int k = rem + (rem >= i ? 1 : 0);
    const float* Ar = AB + (size_t)i * 320;        // A1 row (has +b1 folded)
    const float* Br = AB + (size_t)k * 320 + 160;  // B1 row

    // layer 1: build A-fragments of h1 directly in registers (K padded 150->160)
    bf16x8 af[5];
#pragma unroll
    for (int kk = 0; kk < 5; ++kk) {
        int c = kk * 32 + hi * 8;
        f32x4 a0 = *(const f32x4*)(Ar + c);
        f32x4 a1 = *(const f32x4*)(Ar + c + 4);
        f32x4 b0 = *(const f32x4*)(Br + c);
        f32x4 b1v = *(const f32x4*)(Br + c + 4);
        f32x4 s0 = a0 + b0, s1 = a1 + b1v;
        bf16x8 f;
#pragma unroll
        for (int e = 0; e < 4; ++e) {
            f[e]     = (short)f2bf(fmaxf(s0[e], 0.f));
            f[e + 4] = (short)f2bf(fmaxf(s1[e], 0.f));
        }
        af[kk] = f;
    }

    // layer 2: h2 = relu(h1 @ w2 + b2), write transposed into LDS
#pragma unroll
    for (int nt = 0; nt < 10; ++nt) {
        f32x4 acc = {0.f, 0.f, 0.f, 0.f};
#pragma unroll
        for (int kk = 0; kk < 5; ++kk) {
            bf16x8 b = *(const bf16x8*)(w2p + ((size_t)(kk * 10 + nt) * 64 + lane) * 8);
            acc = mfma16(af[kk], b, acc);
        }
        int col = nt * 16 + m;
        float bb = (col < 150) ? b2[col] : 0.f;
#pragma unroll
        for (int r = 0; r < 4; ++r) {
            float v = fmaxf(acc[r] + bb, 0.f);
            h2t[w][hi * 4 + r][col] = f2bf(v);
        }
    }
    __syncthreads();

    // layer 3: out = h2 @ w3 + b3
    f32x4 acc3 = {0.f, 0.f, 0.f, 0.f};
#pragma unroll
    for (int kk = 0; kk < 5; ++kk) {
        bf16x8 a = *(const bf16x8*)(&h2t[w][m][kk * 32 + hi * 8]);
        bf16x8 b = *(const bf16x8*)(w3p + ((size_t)kk * 64 + lane) * 8);
        acc3 = mfma16(a, b, acc3);
    }
    if (m < 7) {
        float bb = b3[m];
#pragma unroll
        for (int r = 0; r < 4; ++r) {
            int p2 = pb + hi * 4 + r;
            out[p2 * 7 + m] = acc3[r] + bb;
        }
    }
}

extern "C" void kernel_launch(void* const* d_in, const int* in_sizes, int n_in,
                              void* d_out, int out_size, void* d_ws, size_t ws_size,
                              hipStream_t stream) {
    const float* embed  = (const float*)d_in[0];
    const int*   labels = (const int*)d_in[1];
    const float* c1w    = (const float*)d_in[2];
    const float* c1root = (const float*)d_in[3];
    const float* c1b    = (const float*)d_in[4];
    const float* c2w    = (const float*)d_in[5];
    const float* c2root = (const float*)d_in[6];
    const float* c2b    = (const float*)d_in[7];
    // base_* (d_in[8..13]) are dead: their output is never used by the reference
    const float* cw1    = (const float*)d_in[14];
    const float* cb1    = (const float*)d_in[15];
    const float* cw2    = (const float*)d_in[16];
    const float* cb2    = (const float*)d_in[17];
    const float* cw3    = (const float*)d_in[18];
    const float* cb3    = (const float*)d_in[19];
    float* outp = (float*)d_out;
    char* ws = (char*)d_ws;

    u16*   S     = (u16*)(ws + 0);          // [1536][256] bf16        786432
    float* recip = (float*)(ws + 786432);   // [1536] f32              6144
    u16*   Acat1 = (u16*)(ws + 792576);     // [256][5376] bf16        2752512
    u16*   Acat2 = (u16*)(ws + 3545088);    // [256][5376] bf16        2752512
    u16*   Pemb  = (u16*)(ws + 6297600);    // packed embed            393216
    u16*   Px    = (u16*)(ws + 6690816);    // packed x                393216
    u16*   PW1   = (u16*)(ws + 7084032);    // packed Wcat1 [168][48]  8257536
    u16*   PW2   = (u16*)(ws + 15341568);   // packed Wcat2            8257536
    u16*   PC1   = (u16*)(ws + 23599104);   // packed cls_w1 [24][20]  491520
    u16*   Pw2c  = (u16*)(ws + 24090624);   // packed cls_w2 [5][10]   102400
    u16*   Pw3   = (u16*)(ws + 24193024);   // packed cls_w3 [5][1]    10240
    u16*   out2  = (u16*)(ws + 24203264);   // conv2 output bf16       393216
    float* AB    = (float*)(ws + 24596480); // [256][320] f32 A1|B1    327680

    ksetup<<<4422, 256, 0, stream>>>(embed, labels, c1w, c1root, c2w, c2root, cw1, cw2, cw3,
                                     S, recip, Acat1, Pemb, PW1, PW2, PC1, Pw2c, Pw3);
    kmean<<<1152, 256, 0, stream>>>(S, Pemb, recip, Acat1);                    // conv1 aggregate
    kconv<1><<<192, 256, 0, stream>>>(Acat1, PW1, c1b, Acat2, KCAT, 4608, Px); // x = relu(...), + packed Px
    kmean<<<1152, 256, 0, stream>>>(S, Px, recip, Acat2);                      // conv2 aggregate
    kconv<0><<<192, 256, 0, stream>>>(Acat2, PW2, c2b, out2, DD, 0, nullptr);  // out2
    kab<<<80, 256, 0, stream>>>(out2, PC1, cb1, AB);                           // A1(+b1) | B1 tables
    kpair<<<1020, 256, 0, stream>>>(AB, Pw2c, Pw3, cb2, cb3, outp);            // fused pair MLP
}